// Round 5
// baseline (1097.841 us; speedup 1.0000x reference)
//
#include <hip/hip_runtime.h>

// MoE: B=4,S=2048,D=1024,E=8,H=4096,K=2.  T = B*S = 8192 tokens.
// R5: R4 geometry + counted-vmcnt raw-barrier K-loop (T4): prefetch loads stay
// in flight across the barrier; per-wave vmcnt(0) placed BEFORE barrier1 so the
// compiler's drain-before-__syncthreads stall is eliminated.
// ws usage ~407 MB.

#define T_TOK 8192
#define DDIM 1024
#define EEXP 8
#define HDIM 4096
#define RMAX 18432   // T*K + E*256 padding

typedef short short8 __attribute__((ext_vector_type(8)));
typedef float f32x4 __attribute__((ext_vector_type(4)));
typedef unsigned short ushort4v __attribute__((ext_vector_type(4)));
typedef unsigned int u32;

__device__ __forceinline__ unsigned short f2bf(float f) {
  unsigned u = __builtin_bit_cast(unsigned, f);
  return (unsigned short)((u + 0x7FFFu + ((u >> 16) & 1u)) >> 16);
}
__device__ __forceinline__ float bf2f(unsigned short b) {
  unsigned u = ((unsigned)b) << 16;
  return __builtin_bit_cast(float, u);
}
__device__ __forceinline__ void gl_lds16(const void* g, void* l) {
  __builtin_amdgcn_global_load_lds((const u32 __attribute__((address_space(1)))*)g,
                                   (u32 __attribute__((address_space(3)))*)l, 16, 0, 0);
}

// ---- weights: f32 [E][K][N] -> bf16 swizzled tiles [E][ct][kt][16KB] -------
__global__ void k_convert_w(const float* __restrict__ src, unsigned short* __restrict__ dst,
                            int N, int K) {
  __shared__ float lbuf[64 * 129];
  int e = blockIdx.z, ct = blockIdx.x, kt = blockIdx.y;
  int tid = threadIdx.x;
  const float* s = src + (size_t)e * K * N + (size_t)(kt * 64) * N + ct * 128;
#pragma unroll
  for (int q = 0; q < 8; q++) {
    int idx = q * 256 + tid;
    int row = idx >> 5, c4 = (idx & 31) * 4;
    float4 v = *(const float4*)(s + (size_t)row * N + c4);
    lbuf[row * 129 + c4 + 0] = v.x;
    lbuf[row * 129 + c4 + 1] = v.y;
    lbuf[row * 129 + c4 + 2] = v.z;
    lbuf[row * 129 + c4 + 3] = v.w;
  }
  __syncthreads();
  unsigned short* dt = dst + ((size_t)(e * (N / 128) + ct) * (K / 64) + kt) * 8192;
#pragma unroll
  for (int q = 0; q < 4; q++) {
    int idx = q * 256 + tid;
    int kc = idx & 7, n = idx >> 3;
    short8 o;
#pragma unroll
    for (int j = 0; j < 8; j++) o[j] = (short)f2bf(lbuf[(kc * 8 + j) * 129 + n]);
    int byte = (n * 128 + kc * 16) ^ ((n & 7) << 4);
    *(short8*)((char*)dt + byte) = o;
  }
}

// ---- init ------------------------------------------------------------------
__global__ void k_init(int* __restrict__ rowtok, int* __restrict__ counts, int* __restrict__ cursor) {
  int i = blockIdx.x * 256 + threadIdx.x;
  if (i < RMAX) rowtok[i] = 0;
  if (i < EEXP) { counts[i] = 0; cursor[i] = 0; }
}

// ---- gating (+ fused x->bf16) ----------------------------------------------
__launch_bounds__(256)
__global__ void k_gate(const float* __restrict__ x, const float* __restrict__ gw,
                       const float* __restrict__ nwt, const float* __restrict__ noi,
                       int* __restrict__ tki, float* __restrict__ tkp,
                       int* __restrict__ counts, unsigned short* __restrict__ xb) {
  __shared__ float gwT[8][1024];
  int tid = threadIdx.x;
#pragma unroll
  for (int q = 0; q < 32; q++) {
    int flat = q * 256 + tid;
    gwT[flat & 7][flat >> 3] = gw[flat];
  }
  __syncthreads();
  int wave = tid >> 6, l = tid & 63;
  int t = blockIdx.x * 4 + wave;
  float acc[8] = {0.f, 0.f, 0.f, 0.f, 0.f, 0.f, 0.f, 0.f};
  const float4* xr = (const float4*)(x + (size_t)t * DDIM);
#pragma unroll
  for (int i = 0; i < 4; i++) {
    float4 xv = xr[l + i * 64];
    int d0 = (l + i * 64) * 4;
    ushort4v o;
    o.x = f2bf(xv.x); o.y = f2bf(xv.y); o.z = f2bf(xv.z); o.w = f2bf(xv.w);
    *(ushort4v*)(xb + (size_t)t * DDIM + d0) = o;
#pragma unroll
    for (int e = 0; e < 8; e++) {
      float4 gv = *(const float4*)&gwT[e][d0];
      acc[e] += xv.x * gv.x + xv.y * gv.y + xv.z * gv.z + xv.w * gv.w;
    }
  }
#pragma unroll
  for (int s = 1; s < 64; s <<= 1) {
#pragma unroll
    for (int e = 0; e < 8; e++) acc[e] += __shfl_xor(acc[e], s, 64);
  }
  if (l == 0) {
    float nl[8];
#pragma unroll
    for (int e = 0; e < 8; e++) nl[e] = acc[e] + noi[t * 8 + e] * nwt[e];
    int i0 = 0; float v0 = nl[0];
#pragma unroll
    for (int e = 1; e < 8; e++) if (nl[e] > v0) { v0 = nl[e]; i0 = e; }
    int i1 = -1; float v1 = -3.4e38f;
#pragma unroll
    for (int e = 0; e < 8; e++) if (e != i0 && nl[e] > v1) { v1 = nl[e]; i1 = e; }
    float ex = __expf(v1 - v0);
    float p0 = 1.f / (1.f + ex);
    float p1 = ex * p0;
    tki[2 * t] = i0; tki[2 * t + 1] = i1;
    tkp[2 * t] = p0; tkp[2 * t + 1] = p1;
    atomicAdd(&counts[i0], 1);
    atomicAdd(&counts[i1], 1);
  }
}

// ---- prefix (pad to 256-row tiles) -----------------------------------------
__global__ void k_prefix(const int* __restrict__ counts, int* __restrict__ basep) {
  if (threadIdx.x == 0) {
    int b = 0;
    for (int e = 0; e < EEXP; e++) { basep[e] = b; b += (counts[e] + 255) & ~255; }
  }
}

// ---- scatter ---------------------------------------------------------------
__global__ void k_scatter(const int* __restrict__ tki, const int* __restrict__ basep,
                          int* __restrict__ cursor, int* __restrict__ rowtok,
                          int* __restrict__ t2r) {
  int t = blockIdx.x * 256 + threadIdx.x;
  if (t >= T_TOK) return;
#pragma unroll
  for (int k = 0; k < 2; k++) {
    int e = tki[2 * t + k];
    int pos = atomicAdd(&cursor[e], 1);
    int row = basep[e] + pos;
    rowtok[row] = t;
    t2r[2 * t + k] = row;
  }
}

// ---- GEMM1: BM=256, BN=128, BK=64, 512 thr, dbuf + counted-vmcnt -----------
// h = (Xg @ w1 + b1) * silu(Xg @ w2 + b2), bf16 out
__launch_bounds__(512, 2)
__global__ void k_gemm1(const unsigned short* __restrict__ xb,
                        const unsigned short* __restrict__ w1s, const unsigned short* __restrict__ w2s,
                        const float* __restrict__ b1g, const float* __restrict__ b2g,
                        const int* __restrict__ counts, const int* __restrict__ basep,
                        const int* __restrict__ rowtok,
                        unsigned short* __restrict__ hout) {
  int e = blockIdx.y >> 6;
  int rt = blockIdx.y & 63;
  int cnt = counts[e];
  if (rt >= ((cnt + 255) >> 8)) return;
  int ct = blockIdx.x;              // 0..31 over H
  int row0 = basep[e] + rt * 256;
  int col0 = ct * 128;

  __shared__ char smem[131072];     // A dbuf 2x32KB | B1 2x16KB | B2 2x16KB
  __shared__ int s_tok[256];
  __shared__ float s_b1[128], s_b2[128];

  int tid = threadIdx.x;
  if (tid < 256) s_tok[tid] = rowtok[row0 + tid];
  if (tid < 128) {
    s_b1[tid] = b1g[e * HDIM + col0 + tid];
    s_b2[tid] = b2g[e * HDIM + col0 + tid];
  }
  __syncthreads();

  int wave = tid >> 6, l = tid & 63;
  int wm = wave >> 2, wn = wave & 3;          // 2M x 4N
  int g = l >> 4, ln = l & 15;

  // A-staging geometry: chunk c = q*512+tid, r=c>>3, src col8=(c&7)^(r&7)
  size_t a_src[4]; int a_dst[4];
#pragma unroll
  for (int q = 0; q < 4; q++) {
    int c = q * 512 + tid;
    int r = c >> 3, cc = (c & 7) ^ (r & 7);
    a_src[q] = (size_t)s_tok[r] * (DDIM * 2) + cc * 16;   // bytes into xb
    a_dst[q] = c * 16;
  }

  f32x4 zero = {0.f, 0.f, 0.f, 0.f};
  f32x4 acc_a[8][2], acc_b[8][2];
#pragma unroll
  for (int m = 0; m < 8; m++)
#pragma unroll
    for (int n = 0; n < 2; n++) { acc_a[m][n] = zero; acc_b[m][n] = zero; }

  const char* xbb = (const char*)xb;
  const char* w1t = (const char*)(w1s + ((size_t)(e * 32 + ct) * 16) * 8192);
  const char* w2t = (const char*)(w2s + ((size_t)(e * 32 + ct) * 16) * 8192);

#define STAGE1(buf, kt)                                                          \
  {                                                                              \
    int _kt = (kt);                                                              \
    _Pragma("unroll") for (int q = 0; q < 4; q++)                                \
      gl_lds16(xbb + a_src[q] + _kt * 128, smem + (buf) * 32768 + a_dst[q]);     \
    _Pragma("unroll") for (int q = 0; q < 2; q++) {                              \
      int c = q * 512 + tid;                                                     \
      gl_lds16(w1t + (size_t)_kt * 16384 + c * 16, smem + 65536 + (buf) * 16384 + c * 16); \
      gl_lds16(w2t + (size_t)_kt * 16384 + c * 16, smem + 98304 + (buf) * 16384 + c * 16); \
    }                                                                            \
  }

  STAGE1(0, 0);

  int cur = 0;
  for (int kt = 0; kt < 16; kt++) {
    // wait for THIS wave's loads of buf `cur` (issued last iter, hidden under
    // last iter's MFMA phase), then barrier WITHOUT a compiler drain.
    asm volatile("s_waitcnt vmcnt(0)" ::: "memory");
    __builtin_amdgcn_s_barrier();
    if (kt < 15) STAGE1(cur ^ 1, kt + 1);   // stays in flight across barrier2
#pragma unroll
    for (int ks = 0; ks < 2; ks++) {
      int kb = ks * 64 + g * 16;
      short8 af[8], bf1[2], bf2[2];
#pragma unroll
      for (int m = 0; m < 8; m++) {
        int r = wm * 128 + m * 16 + ln;
        af[m] = *(const short8*)(smem + cur * 32768 + ((r * 128 + kb) ^ ((r & 7) << 4)));
      }
#pragma unroll
      for (int n = 0; n < 2; n++) {
        int r = wn * 32 + n * 16 + ln;
        int byte = (r * 128 + kb) ^ ((r & 7) << 4);
        bf1[n] = *(const short8*)(smem + 65536 + cur * 16384 + byte);
        bf2[n] = *(const short8*)(smem + 98304 + cur * 16384 + byte);
      }
#pragma unroll
      for (int m = 0; m < 8; m++)
#pragma unroll
        for (int n = 0; n < 2; n++) {
          acc_a[m][n] = __builtin_amdgcn_mfma_f32_16x16x32_bf16(af[m], bf1[n], acc_a[m][n], 0, 0, 0);
          acc_b[m][n] = __builtin_amdgcn_mfma_f32_16x16x32_bf16(af[m], bf2[n], acc_b[m][n], 0, 0, 0);
        }
    }
    __builtin_amdgcn_s_barrier();
    cur ^= 1;
  }

  // epilogue: SwiGLU -> bf16 tile (256x128) in LDS, coalesced stores
  unsigned short* ht = (unsigned short*)smem;
#pragma unroll
  for (int m = 0; m < 8; m++)
#pragma unroll
    for (int n = 0; n < 2; n++)
#pragma unroll
      for (int r = 0; r < 4; r++) {
        int row = wm * 128 + m * 16 + g * 4 + r;
        int col = wn * 32 + n * 16 + ln;
        float a = acc_a[m][n][r] + s_b1[col];
        float b = acc_b[m][n][r] + s_b2[col];
        float hv = a * (b / (1.f + __expf(-b)));
        ht[row * 128 + col] = f2bf(hv);
      }
  __syncthreads();
#pragma unroll
  for (int q = 0; q < 8; q++) {
    int idx = q * 512 + tid;          // 4096 chunks of 16B; 16 chunks per 256B row
    int row = idx >> 4, cc = (idx & 15) * 8;
    short8 v = *(const short8*)(smem + idx * 16);
    *(short8*)(hout + (size_t)(row0 + row) * HDIM + col0 + cc) = v;
  }
}

// ---- GEMM2: BM=128, BN=256, BK=64, 512 thr, dbuf + counted-vmcnt -----------
__launch_bounds__(512, 2)
__global__ void k_gemm2(const unsigned short* __restrict__ hin,
                        const unsigned short* __restrict__ wps, const float* __restrict__ bpg,
                        const int* __restrict__ counts, const int* __restrict__ basep,
                        unsigned short* __restrict__ yout) {
  int e = blockIdx.y >> 6;
  int rt = blockIdx.y & 63;
  int cnt = counts[e];
  if (rt >= ((cnt + 127) >> 7)) return;
  int ct = blockIdx.x;              // 0..3 over D (256 cols each)
  int row0 = basep[e] + rt * 128;
  int col0 = ct * 256;

  __shared__ char smem[98304];      // A dbuf 2x16KB | B dbuf 2x32KB
  __shared__ float s_bp[256];
  int tid = threadIdx.x;
  if (tid < 256) s_bp[tid] = bpg[e * DDIM + col0 + tid];
  __syncthreads();

  int wave = tid >> 6, l = tid & 63;
  int wm = wave >> 2, wn = wave & 3;          // 2M x 4N
  int g = l >> 4, ln = l & 15;

  size_t a_src[2]; int a_dst[2];
#pragma unroll
  for (int q = 0; q < 2; q++) {
    int c = q * 512 + tid;
    int r = c >> 3, cc = (c & 7) ^ (r & 7);
    a_src[q] = (size_t)(row0 + r) * (HDIM * 2) + cc * 16;
    a_dst[q] = c * 16;
  }

  f32x4 zero = {0.f, 0.f, 0.f, 0.f};
  f32x4 acc[4][4];
#pragma unroll
  for (int m = 0; m < 4; m++)
#pragma unroll
    for (int n = 0; n < 4; n++) acc[m][n] = zero;

  const char* hb = (const char*)hin;
  const char* wpt = (const char*)(wps + ((size_t)(e * 8 + ct * 2) * 64) * 8192);
  // tile (sub, kt) at wpt + (sub*64 + kt)*16384 bytes, sub in {0,1}

#define STAGE2(buf, kt)                                                          \
  {                                                                              \
    int _kt = (kt);                                                              \
    _Pragma("unroll") for (int q = 0; q < 2; q++)                                \
      gl_lds16(hb + a_src[q] + _kt * 128, smem + (buf) * 16384 + a_dst[q]);      \
    _Pragma("unroll") for (int q = 0; q < 4; q++) {                              \
      int c = q * 512 + tid;                                                     \
      int sub = c >> 10;                                                         \
      gl_lds16(wpt + (size_t)(sub * 64 + _kt) * 16384 + (c & 1023) * 16,         \
               smem + 32768 + (buf) * 32768 + c * 16);                           \
    }                                                                            \
  }

  STAGE2(0, 0);

  int cur = 0;
  for (int kt = 0; kt < 64; kt++) {
    asm volatile("s_waitcnt vmcnt(0)" ::: "memory");
    __builtin_amdgcn_s_barrier();
    if (kt < 63) STAGE2(cur ^ 1, kt + 1);
#pragma unroll
    for (int ks = 0; ks < 2; ks++) {
      int kb = ks * 64 + g * 16;
      short8 af[4], bf[4];
#pragma unroll
      for (int m = 0; m < 4; m++) {
        int r = wm * 64 + m * 16 + ln;
        af[m] = *(const short8*)(smem + cur * 16384 + ((r * 128 + kb) ^ ((r & 7) << 4)));
      }
#pragma unroll
      for (int n = 0; n < 4; n++) {
        int rg = wn * 64 + n * 16 + ln;         // 0..255
        int sub = rg >> 7, rr = rg & 127;
        bf[n] = *(const short8*)(smem + 32768 + cur * 32768 + sub * 16384 +
                                 ((rr * 128 + kb) ^ ((rr & 7) << 4)));
      }
#pragma unroll
      for (int m = 0; m < 4; m++)
#pragma unroll
        for (int n = 0; n < 4; n++)
          acc[m][n] = __builtin_amdgcn_mfma_f32_16x16x32_bf16(af[m], bf[n], acc[m][n], 0, 0, 0);
    }
    __builtin_amdgcn_s_barrier();
    cur ^= 1;
  }

  // epilogue: 128x256 bf16 tile in LDS, coalesced stores
  unsigned short* ht = (unsigned short*)smem;
#pragma unroll
  for (int m = 0; m < 4; m++)
#pragma unroll
    for (int n = 0; n < 4; n++)
#pragma unroll
      for (int r = 0; r < 4; r++) {
        int row = wm * 64 + m * 16 + g * 4 + r;
        int col = wn * 64 + n * 16 + ln;
        ht[row * 256 + col] = f2bf(acc[m][n][r] + s_bp[col]);
      }
  __syncthreads();
#pragma unroll
  for (int q = 0; q < 8; q++) {
    int idx = q * 512 + tid;          // 4096 chunks of 16B; 32 chunks per 512B row
    int row = idx >> 5, cc = (idx & 31) * 8;
    short8 v = *(const short8*)(smem + idx * 16);
    *(short8*)(yout + (size_t)(row0 + row) * DDIM + col0 + cc) = v;
  }
}

// ---- combine ---------------------------------------------------------------
__global__ void k_combine(const unsigned short* __restrict__ yv,
                          const int* __restrict__ t2r, const float* __restrict__ tkp,
                          float* __restrict__ outp) {
  int gid = blockIdx.x * 256 + threadIdx.x;
  int t = gid >> 8;
  int c4 = (gid & 255) << 2;
  int r0 = t2r[2 * t], r1 = t2r[2 * t + 1];
  float p0 = tkp[2 * t], p1 = tkp[2 * t + 1];
  ushort4v u0 = *(const ushort4v*)(yv + (size_t)r0 * DDIM + c4);
  ushort4v u1 = *(const ushort4v*)(yv + (size_t)r1 * DDIM + c4);
  float4 o;
  o.x = p0 * bf2f(u0.x) + p1 * bf2f(u1.x);
  o.y = p0 * bf2f(u0.y) + p1 * bf2f(u1.y);
  o.z = p0 * bf2f(u0.z) + p1 * bf2f(u1.z);
  o.w = p0 * bf2f(u0.w) + p1 * bf2f(u1.w);
  *(float4*)(outp + (size_t)t * DDIM + c4) = o;
}

extern "C" void kernel_launch(void* const* d_in, const int* in_sizes, int n_in,
                              void* d_out, int out_size, void* d_ws, size_t ws_size,
                              hipStream_t stream) {
  const float* x   = (const float*)d_in[0];
  const float* gw  = (const float*)d_in[1];
  const float* nwt = (const float*)d_in[2];
  const float* noi = (const float*)d_in[3];
  const float* w1  = (const float*)d_in[4];
  const float* b1  = (const float*)d_in[5];
  const float* w2  = (const float*)d_in[6];
  const float* b2  = (const float*)d_in[7];
  const float* wp  = (const float*)d_in[8];
  const float* bp  = (const float*)d_in[9];
  float* outp = (float*)d_out;
  char* ws = (char*)d_ws;

  constexpr size_t SZ_W = (size_t)EEXP * DDIM * HDIM * 2;
  constexpr size_t OFF_XB  = 0;
  constexpr size_t OFF_W1S = OFF_XB + (size_t)T_TOK * DDIM * 2;
  constexpr size_t OFF_W2S = OFF_W1S + SZ_W;
  constexpr size_t OFF_WPS = OFF_W2S + SZ_W;
  constexpr size_t OFF_H   = OFF_WPS + SZ_W;
  constexpr size_t OFF_Y   = OFF_H + (size_t)RMAX * HDIM * 2;
  constexpr size_t OFF_RT  = OFF_Y + (size_t)RMAX * DDIM * 2;
  constexpr size_t OFF_TKI = OFF_RT + (size_t)RMAX * 4;
  constexpr size_t OFF_TKP = OFF_TKI + (size_t)T_TOK * 2 * 4;
  constexpr size_t OFF_T2R = OFF_TKP + (size_t)T_TOK * 2 * 4;
  constexpr size_t OFF_CNT = OFF_T2R + (size_t)T_TOK * 2 * 4;
  constexpr size_t OFF_BAS = OFF_CNT + 256;
  constexpr size_t OFF_CUR = OFF_BAS + 256;
  // total ~407 MB

  unsigned short* xb  = (unsigned short*)(ws + OFF_XB);
  unsigned short* w1s = (unsigned short*)(ws + OFF_W1S);
  unsigned short* w2s = (unsigned short*)(ws + OFF_W2S);
  unsigned short* wps = (unsigned short*)(ws + OFF_WPS);
  unsigned short* h   = (unsigned short*)(ws + OFF_H);
  unsigned short* y   = (unsigned short*)(ws + OFF_Y);
  int*   rowtok = (int*)(ws + OFF_RT);
  int*   tki    = (int*)(ws + OFF_TKI);
  float* tkp    = (float*)(ws + OFF_TKP);
  int*   t2r    = (int*)(ws + OFF_T2R);
  int*   counts = (int*)(ws + OFF_CNT);
  int*   basep  = (int*)(ws + OFF_BAS);
  int*   cursor = (int*)(ws + OFF_CUR);

  dim3 blk(256);
  k_init<<<dim3((RMAX + 255) / 256), blk, 0, stream>>>(rowtok, counts, cursor);
  k_gate<<<dim3(T_TOK / 4), blk, 0, stream>>>(x, gw, nwt, noi, tki, tkp, counts, xb);
  k_convert_w<<<dim3(HDIM / 128, DDIM / 64, EEXP), blk, 0, stream>>>(w1, w1s, HDIM, DDIM);
  k_convert_w<<<dim3(HDIM / 128, DDIM / 64, EEXP), blk, 0, stream>>>(w2, w2s, HDIM, DDIM);
  k_convert_w<<<dim3(DDIM / 128, HDIM / 64, EEXP), blk, 0, stream>>>(wp, wps, DDIM, HDIM);
  k_prefix<<<dim3(1), dim3(64), 0, stream>>>(counts, basep);
  k_scatter<<<dim3(T_TOK / 256), blk, 0, stream>>>(tki, basep, cursor, rowtok, t2r);
  k_gemm1<<<dim3(HDIM / 128, EEXP * 64), dim3(512), 0, stream>>>(xb, w1s, w2s, b1, b2, counts, basep, rowtok, h);
  k_gemm2<<<dim3(DDIM / 256, EEXP * 64), dim3(512), 0, stream>>>(h, wps, bp, counts, basep, y);
  k_combine<<<dim3(T_TOK), blk, 0, stream>>>(y, t2r, tkp, outp);
  (void)in_sizes; (void)n_in; (void)out_size; (void)ws_size;
}

// Round 6
// 1040.701 us; speedup vs baseline: 1.0549x; 1.0549x over previous
//
#include <hip/hip_runtime.h>

// MoE: B=4,S=2048,D=1024,E=8,H=4096,K=2.  T = B*S = 8192 tokens.
// R6: 4-slot (BK=32) 3-deep counted-vmcnt pipeline, 2 phases/slot with
// {ds_read | gl_lds issue | s_barrier | setprio MFMA}, never vmcnt(0) in loop.
// Pre-swizzled 8KB weight tiles (128n x 32k, XOR (n&3)<<4).
// ws usage ~407 MB.

#define T_TOK 8192
#define DDIM 1024
#define EEXP 8
#define HDIM 4096
#define RMAX 18432   // T*K + E*256 padding

typedef short short8 __attribute__((ext_vector_type(8)));
typedef float f32x4 __attribute__((ext_vector_type(4)));
typedef unsigned short ushort4v __attribute__((ext_vector_type(4)));
typedef unsigned int u32;

__device__ __forceinline__ unsigned short f2bf(float f) {
  unsigned u = __builtin_bit_cast(unsigned, f);
  return (unsigned short)((u + 0x7FFFu + ((u >> 16) & 1u)) >> 16);
}
__device__ __forceinline__ float bf2f(unsigned short b) {
  unsigned u = ((unsigned)b) << 16;
  return __builtin_bit_cast(float, u);
}
__device__ __forceinline__ void gl_lds16(const void* g, void* l) {
  __builtin_amdgcn_global_load_lds((const u32 __attribute__((address_space(1)))*)g,
                                   (u32 __attribute__((address_space(3)))*)l, 16, 0, 0);
}
#define BAR() asm volatile("s_barrier" ::: "memory")
__device__ __forceinline__ void vwait_c(int n) {
  if (n == 8) asm volatile("s_waitcnt vmcnt(8)" ::: "memory");
  else if (n == 4) asm volatile("s_waitcnt vmcnt(4)" ::: "memory");
  else if (n == 0) asm volatile("s_waitcnt vmcnt(0)" ::: "memory");
}
#define MFMA_BF16 __builtin_amdgcn_mfma_f32_16x16x32_bf16

// ---- weights: f32 [E][K][N] -> bf16 swizzled 8KB tiles [E][ctn][kt32] ------
// Tile = 128 n x 32 k; byte (n*64 + kc*16) ^ ((n&3)<<4) holds B^T[n][kc*8..+7].
__global__ void k_convert_w(const float* __restrict__ src, unsigned short* __restrict__ dst,
                            int N, int K) {
  __shared__ float lbuf[32][130];
  int e = blockIdx.z, ct = blockIdx.x, kt = blockIdx.y;
  int tid = threadIdx.x;
  const float* s = src + (size_t)e * K * N + (size_t)(kt * 32) * N + ct * 128;
#pragma unroll
  for (int q = 0; q < 4; q++) {
    int idx = q * 256 + tid;
    int row = idx >> 5, c4 = (idx & 31) * 4;
    float4 v = *(const float4*)(s + (size_t)row * N + c4);
    lbuf[row][c4 + 0] = v.x; lbuf[row][c4 + 1] = v.y;
    lbuf[row][c4 + 2] = v.z; lbuf[row][c4 + 3] = v.w;
  }
  __syncthreads();
  char* dt = (char*)dst + ((size_t)(e * (N / 128) + ct) * (K / 32) + kt) * 8192;
#pragma unroll
  for (int q = 0; q < 2; q++) {
    int idx = q * 256 + tid;
    int n = idx >> 2, kc = idx & 3;
    short8 o;
#pragma unroll
    for (int j = 0; j < 8; j++) o[j] = (short)f2bf(lbuf[kc * 8 + j][n]);
    *(short8*)(dt + ((n * 64 + kc * 16) ^ ((n & 3) << 4))) = o;
  }
}

// ---- init ------------------------------------------------------------------
__global__ void k_init(int* __restrict__ rowtok, int* __restrict__ counts, int* __restrict__ cursor) {
  int i = blockIdx.x * 256 + threadIdx.x;
  if (i < RMAX) rowtok[i] = 0;
  if (i < EEXP) { counts[i] = 0; cursor[i] = 0; }
}

// ---- gating (+ fused x->bf16) ----------------------------------------------
__launch_bounds__(256)
__global__ void k_gate(const float* __restrict__ x, const float* __restrict__ gw,
                       const float* __restrict__ nwt, const float* __restrict__ noi,
                       int* __restrict__ tki, float* __restrict__ tkp,
                       int* __restrict__ counts, unsigned short* __restrict__ xb) {
  __shared__ float gwT[8][1024];
  int tid = threadIdx.x;
#pragma unroll
  for (int q = 0; q < 32; q++) {
    int flat = q * 256 + tid;
    gwT[flat & 7][flat >> 3] = gw[flat];
  }
  __syncthreads();
  int wave = tid >> 6, l = tid & 63;
  int t = blockIdx.x * 4 + wave;
  float acc[8] = {0.f, 0.f, 0.f, 0.f, 0.f, 0.f, 0.f, 0.f};
  const float4* xr = (const float4*)(x + (size_t)t * DDIM);
#pragma unroll
  for (int i = 0; i < 4; i++) {
    float4 xv = xr[l + i * 64];
    int d0 = (l + i * 64) * 4;
    ushort4v o;
    o.x = f2bf(xv.x); o.y = f2bf(xv.y); o.z = f2bf(xv.z); o.w = f2bf(xv.w);
    *(ushort4v*)(xb + (size_t)t * DDIM + d0) = o;
#pragma unroll
    for (int e = 0; e < 8; e++) {
      float4 gv = *(const float4*)&gwT[e][d0];
      acc[e] += xv.x * gv.x + xv.y * gv.y + xv.z * gv.z + xv.w * gv.w;
    }
  }
#pragma unroll
  for (int s = 1; s < 64; s <<= 1) {
#pragma unroll
    for (int e = 0; e < 8; e++) acc[e] += __shfl_xor(acc[e], s, 64);
  }
  if (l == 0) {
    float nl[8];
#pragma unroll
    for (int e = 0; e < 8; e++) nl[e] = acc[e] + noi[t * 8 + e] * nwt[e];
    int i0 = 0; float v0 = nl[0];
#pragma unroll
    for (int e = 1; e < 8; e++) if (nl[e] > v0) { v0 = nl[e]; i0 = e; }
    int i1 = -1; float v1 = -3.4e38f;
#pragma unroll
    for (int e = 0; e < 8; e++) if (e != i0 && nl[e] > v1) { v1 = nl[e]; i1 = e; }
    float ex = __expf(v1 - v0);
    float p0 = 1.f / (1.f + ex);
    float p1 = ex * p0;
    tki[2 * t] = i0; tki[2 * t + 1] = i1;
    tkp[2 * t] = p0; tkp[2 * t + 1] = p1;
    atomicAdd(&counts[i0], 1);
    atomicAdd(&counts[i1], 1);
  }
}

// ---- prefix (pad to 256-row tiles) -----------------------------------------
__global__ void k_prefix(const int* __restrict__ counts, int* __restrict__ basep) {
  if (threadIdx.x == 0) {
    int b = 0;
    for (int e = 0; e < EEXP; e++) { basep[e] = b; b += (counts[e] + 255) & ~255; }
  }
}

// ---- scatter ---------------------------------------------------------------
__global__ void k_scatter(const int* __restrict__ tki, const int* __restrict__ basep,
                          int* __restrict__ cursor, int* __restrict__ rowtok,
                          int* __restrict__ t2r) {
  int t = blockIdx.x * 256 + threadIdx.x;
  if (t >= T_TOK) return;
#pragma unroll
  for (int k = 0; k < 2; k++) {
    int e = tki[2 * t + k];
    int pos = atomicAdd(&cursor[e], 1);
    int row = basep[e] + pos;
    rowtok[row] = t;
    t2r[2 * t + k] = row;
  }
}

// ---- GEMM1: BM=256, BN=128(x2 B), BK=32, 4 slots, 3-deep pipeline ----------
__launch_bounds__(512, 2)
__global__ void k_gemm1(const unsigned short* __restrict__ xb,
                        const unsigned short* __restrict__ w1s, const unsigned short* __restrict__ w2s,
                        const float* __restrict__ b1g, const float* __restrict__ b2g,
                        const int* __restrict__ counts, const int* __restrict__ basep,
                        const int* __restrict__ rowtok,
                        unsigned short* __restrict__ hout) {
  int e = blockIdx.y >> 6;
  int rt = blockIdx.y & 63;
  int cnt = counts[e];
  if (rt >= ((cnt + 255) >> 8)) return;
  int ct = blockIdx.x;              // 0..31 over H
  int row0 = basep[e] + rt * 256;
  int col0 = ct * 128;

  __shared__ char smem[131072];     // A 4x16KB @0 | B1 4x8KB @65536 | B2 4x8KB @98304
  __shared__ int s_tok[256];
  __shared__ float s_b1[128], s_b2[128];

  int tid = threadIdx.x;
  if (tid < 256) s_tok[tid] = rowtok[row0 + tid];
  if (tid < 128) {
    s_b1[tid] = b1g[e * HDIM + col0 + tid];
    s_b2[tid] = b2g[e * HDIM + col0 + tid];
  }
  __syncthreads();

  int wave = tid >> 6, l = tid & 63;
  int wm = wave >> 2, wn = wave & 3;          // 2M x 4N
  int g = l >> 4, ln = l & 15;

  // A staging: 2 chunks/thread. chunk c: r=c>>2, kc=c&3, src col pre-XORed.
  int c0 = tid, c1 = 512 + tid;
  int r0s = c0 >> 2, k0s = c0 & 3, r1s = c1 >> 2, k1s = c1 & 3;
  size_t a_src0 = (size_t)s_tok[r0s] * 2048 + (size_t)((k0s ^ (r0s & 3)) * 16);
  size_t a_src1 = (size_t)s_tok[r1s] * 2048 + (size_t)((k1s ^ (r1s & 3)) * 16);
  int a_dst0 = c0 * 16, a_dst1 = c1 * 16;

  int a_rd[8];
#pragma unroll
  for (int m = 0; m < 8; m++) {
    int r = wm * 128 + m * 16 + ln;
    a_rd[m] = r * 64 + ((g * 16) ^ ((r & 3) << 4));
  }
  int b_rd[2];
#pragma unroll
  for (int n = 0; n < 2; n++) {
    int r = wn * 32 + n * 16 + ln;
    b_rd[n] = r * 64 + ((g * 16) ^ ((r & 3) << 4));
  }

  f32x4 zero = {0.f, 0.f, 0.f, 0.f};
  f32x4 acc_a[8][2], acc_b[8][2];
#pragma unroll
  for (int m = 0; m < 8; m++)
#pragma unroll
    for (int n = 0; n < 2; n++) { acc_a[m][n] = zero; acc_b[m][n] = zero; }

  const char* xbb = (const char*)xb;
  const char* w1t = (const char*)w1s + (size_t)(e * 32 + ct) * 32 * 8192;
  const char* w2t = (const char*)w2s + (size_t)(e * 32 + ct) * 32 * 8192;

#define G1_PRE(s) { int nb = (s) & 3;                                            \
    gl_lds16(xbb + a_src0 + (size_t)(s) * 64, smem + nb * 16384 + a_dst0);       \
    gl_lds16(xbb + a_src1 + (size_t)(s) * 64, smem + nb * 16384 + a_dst1);       \
    gl_lds16(w1t + (size_t)(s) * 8192 + tid * 16, smem + 65536 + nb * 8192 + tid * 16); \
    gl_lds16(w2t + (size_t)(s) * 8192 + tid * 16, smem + 98304 + nb * 8192 + tid * 16); }

  G1_PRE(0) G1_PRE(1) G1_PRE(2)
  vwait_c(8); BAR();

#define G1_SLOT(s, ISSUE, VMN) {                                                 \
    int bs = (s) & 3;                                                            \
    char* Ab = smem + bs * 16384;                                                \
    char* B1b = smem + 65536 + bs * 8192;                                        \
    char* B2b = smem + 98304 + bs * 8192;                                        \
    short8 af[4], b1f[2], b2f[2];                                                \
    _Pragma("unroll") for (int m = 0; m < 4; m++) af[m] = *(const short8*)(Ab + a_rd[m]); \
    b1f[0] = *(const short8*)(B1b + b_rd[0]); b1f[1] = *(const short8*)(B1b + b_rd[1]); \
    b2f[0] = *(const short8*)(B2b + b_rd[0]); b2f[1] = *(const short8*)(B2b + b_rd[1]); \
    if (ISSUE) { int ns = (s) + 3, nb = ns & 3;                                  \
      gl_lds16(xbb + a_src0 + (size_t)ns * 64, smem + nb * 16384 + a_dst0);      \
      gl_lds16(xbb + a_src1 + (size_t)ns * 64, smem + nb * 16384 + a_dst1); }    \
    BAR();                                                                       \
    __builtin_amdgcn_s_setprio(1);                                               \
    _Pragma("unroll") for (int m = 0; m < 4; m++) {                              \
      acc_a[m][0] = MFMA_BF16(af[m], b1f[0], acc_a[m][0], 0, 0, 0);              \
      acc_a[m][1] = MFMA_BF16(af[m], b1f[1], acc_a[m][1], 0, 0, 0);              \
      acc_b[m][0] = MFMA_BF16(af[m], b2f[0], acc_b[m][0], 0, 0, 0);              \
      acc_b[m][1] = MFMA_BF16(af[m], b2f[1], acc_b[m][1], 0, 0, 0); }            \
    __builtin_amdgcn_s_setprio(0);                                               \
    BAR();                                                                       \
    _Pragma("unroll") for (int m = 0; m < 4; m++) af[m] = *(const short8*)(Ab + a_rd[4 + m]); \
    if (ISSUE) { int ns = (s) + 3, nb = ns & 3;                                  \
      gl_lds16(w1t + (size_t)ns * 8192 + tid * 16, smem + 65536 + nb * 8192 + tid * 16); \
      gl_lds16(w2t + (size_t)ns * 8192 + tid * 16, smem + 98304 + nb * 8192 + tid * 16); } \
    BAR();                                                                       \
    __builtin_amdgcn_s_setprio(1);                                               \
    _Pragma("unroll") for (int m = 0; m < 4; m++) {                              \
      acc_a[4 + m][0] = MFMA_BF16(af[m], b1f[0], acc_a[4 + m][0], 0, 0, 0);      \
      acc_a[4 + m][1] = MFMA_BF16(af[m], b1f[1], acc_a[4 + m][1], 0, 0, 0);      \
      acc_b[4 + m][0] = MFMA_BF16(af[m], b2f[0], acc_b[4 + m][0], 0, 0, 0);      \
      acc_b[4 + m][1] = MFMA_BF16(af[m], b2f[1], acc_b[4 + m][1], 0, 0, 0); }    \
    __builtin_amdgcn_s_setprio(0);                                               \
    vwait_c(VMN); BAR(); }

  for (int s = 0; s < 29; ++s) { G1_SLOT(s, 1, 8) }
  G1_SLOT(29, 0, 4)
  G1_SLOT(30, 0, 0)
  G1_SLOT(31, 0, -1)

  __syncthreads();
  // epilogue: SwiGLU -> bf16 tile (256x128) in LDS, coalesced stores
  unsigned short* ht = (unsigned short*)smem;
#pragma unroll
  for (int m = 0; m < 8; m++)
#pragma unroll
    for (int n = 0; n < 2; n++)
#pragma unroll
      for (int r = 0; r < 4; r++) {
        int row = wm * 128 + m * 16 + g * 4 + r;
        int col = wn * 32 + n * 16 + ln;
        float a = acc_a[m][n][r] + s_b1[col];
        float b = acc_b[m][n][r] + s_b2[col];
        float hv = a * (b / (1.f + __expf(-b)));
        ht[row * 128 + col] = f2bf(hv);
      }
  __syncthreads();
#pragma unroll
  for (int q = 0; q < 8; q++) {
    int idx = q * 512 + tid;          // 4096 chunks; 16 per 256B row
    int row = idx >> 4, cc = (idx & 15) * 8;
    short8 v = *(const short8*)(smem + idx * 16);
    *(short8*)(hout + (size_t)(row0 + row) * HDIM + col0 + cc) = v;
  }
}

// ---- GEMM2: BM=256, BN=256, BK=32, 4 slots, 3-deep pipeline ----------------
__launch_bounds__(512, 2)
__global__ void k_gemm2(const unsigned short* __restrict__ hin,
                        const unsigned short* __restrict__ wps, const float* __restrict__ bpg,
                        const int* __restrict__ counts, const int* __restrict__ basep,
                        unsigned short* __restrict__ yout) {
  int e = blockIdx.y >> 6;
  int rt = blockIdx.y & 63;
  int cnt = counts[e];
  if (rt >= ((cnt + 255) >> 8)) return;
  int ct = blockIdx.x;              // 0..3 over D (256 cols)
  int row0 = basep[e] + rt * 256;
  int col0 = ct * 256;

  __shared__ char smem[131072];     // A 4x16KB @0 | B 4x16KB @65536
  __shared__ float s_bp[256];
  int tid = threadIdx.x;
  if (tid < 256) s_bp[tid] = bpg[e * DDIM + col0 + tid];
  __syncthreads();

  int wave = tid >> 6, l = tid & 63;
  int wm = wave >> 2, wn = wave & 3;          // 2M x 4N -> per wave 128x64
  int g = l >> 4, ln = l & 15;

  int c0 = tid, c1 = 512 + tid;
  int r0s = c0 >> 2, k0s = c0 & 3, r1s = c1 >> 2, k1s = c1 & 3;
  size_t a_src0 = (size_t)(row0 + r0s) * 8192 + (size_t)((k0s ^ (r0s & 3)) * 16);
  size_t a_src1 = (size_t)(row0 + r1s) * 8192 + (size_t)((k1s ^ (r1s & 3)) * 16);
  int a_dst0 = c0 * 16, a_dst1 = c1 * 16;
  // B staging: c0 -> subtile 0 (cols ct*256..+127), c1 -> subtile 1
  const char* b_src0 = (const char*)wps + (size_t)(e * 8 + ct * 2 + 0) * 128 * 8192 + (size_t)(c0 & 511) * 16;
  const char* b_src1 = (const char*)wps + (size_t)(e * 8 + ct * 2 + 1) * 128 * 8192 + (size_t)(c1 & 511) * 16;

  int a_rd[8];
#pragma unroll
  for (int m = 0; m < 8; m++) {
    int r = wm * 128 + m * 16 + ln;
    a_rd[m] = r * 64 + ((g * 16) ^ ((r & 3) << 4));
  }
  int b_rd[4];
#pragma unroll
  for (int n = 0; n < 4; n++) {
    int ncol = wn * 64 + n * 16 + ln;
    int sub = ncol >> 7, r = ncol & 127;
    b_rd[n] = sub * 8192 + r * 64 + ((g * 16) ^ ((r & 3) << 4));
  }

  f32x4 zero = {0.f, 0.f, 0.f, 0.f};
  f32x4 acc[8][4];
#pragma unroll
  for (int m = 0; m < 8; m++)
#pragma unroll
    for (int n = 0; n < 4; n++) acc[m][n] = zero;

  const char* hb = (const char*)hin;

#define G2_PRE(s) { int nb = (s) & 3;                                            \
    gl_lds16(hb + a_src0 + (size_t)(s) * 64, smem + nb * 16384 + a_dst0);        \
    gl_lds16(hb + a_src1 + (size_t)(s) * 64, smem + nb * 16384 + a_dst1);        \
    gl_lds16(b_src0 + (size_t)(s) * 8192, smem + 65536 + nb * 16384 + a_dst0);   \
    gl_lds16(b_src1 + (size_t)(s) * 8192, smem + 65536 + nb * 16384 + a_dst1); }

  G2_PRE(0) G2_PRE(1) G2_PRE(2)
  vwait_c(8); BAR();

#define G2_SLOT(s, ISSUE, VMN) {                                                 \
    int bs = (s) & 3;                                                            \
    char* Ab = smem + bs * 16384;                                                \
    char* Bb = smem + 65536 + bs * 16384;                                        \
    short8 af[4], bf[4];                                                         \
    _Pragma("unroll") for (int m = 0; m < 4; m++) af[m] = *(const short8*)(Ab + a_rd[m]); \
    _Pragma("unroll") for (int n = 0; n < 4; n++) bf[n] = *(const short8*)(Bb + b_rd[n]); \
    if (ISSUE) { int ns = (s) + 3, nb = ns & 3;                                  \
      gl_lds16(hb + a_src0 + (size_t)ns * 64, smem + nb * 16384 + a_dst0);       \
      gl_lds16(hb + a_src1 + (size_t)ns * 64, smem + nb * 16384 + a_dst1); }     \
    BAR();                                                                       \
    __builtin_amdgcn_s_setprio(1);                                               \
    _Pragma("unroll") for (int m = 0; m < 4; m++)                                \
      _Pragma("unroll") for (int n = 0; n < 4; n++)                              \
        acc[m][n] = MFMA_BF16(af[m], bf[n], acc[m][n], 0, 0, 0);                 \
    __builtin_amdgcn_s_setprio(0);                                               \
    BAR();                                                                       \
    _Pragma("unroll") for (int m = 0; m < 4; m++) af[m] = *(const short8*)(Ab + a_rd[4 + m]); \
    if (ISSUE) { int ns = (s) + 3, nb = ns & 3;                                  \
      gl_lds16(b_src0 + (size_t)ns * 8192, smem + 65536 + nb * 16384 + a_dst0);  \
      gl_lds16(b_src1 + (size_t)ns * 8192, smem + 65536 + nb * 16384 + a_dst1); }\
    BAR();                                                                       \
    __builtin_amdgcn_s_setprio(1);                                               \
    _Pragma("unroll") for (int m = 0; m < 4; m++)                                \
      _Pragma("unroll") for (int n = 0; n < 4; n++)                              \
        acc[4 + m][n] = MFMA_BF16(af[m], bf[n], acc[4 + m][n], 0, 0, 0);         \
    __builtin_amdgcn_s_setprio(0);                                               \
    vwait_c(VMN); BAR(); }

  for (int s = 0; s < 125; ++s) { G2_SLOT(s, 1, 8) }
  G2_SLOT(125, 0, 4)
  G2_SLOT(126, 0, 0)
  G2_SLOT(127, 0, -1)

  __syncthreads();
  // epilogue: 256x256 bf16 tile in LDS, coalesced stores
  unsigned short* ht = (unsigned short*)smem;
#pragma unroll
  for (int m = 0; m < 8; m++)
#pragma unroll
    for (int n = 0; n < 4; n++)
#pragma unroll
      for (int r = 0; r < 4; r++) {
        int row = wm * 128 + m * 16 + g * 4 + r;
        int col = wn * 64 + n * 16 + ln;
        ht[row * 256 + col] = f2bf(acc[m][n][r] + s_bp[col]);
      }
  __syncthreads();
#pragma unroll
  for (int q = 0; q < 16; q++) {
    int idx = q * 512 + tid;          // 8192 chunks; 32 per 512B row
    int row = idx >> 5, cc = (idx & 31) * 8;
    short8 v = *(const short8*)(smem + idx * 16);
    *(short8*)(yout + (size_t)(row0 + row) * DDIM + col0 + cc) = v;
  }
}

// ---- combine ---------------------------------------------------------------
__global__ void k_combine(const unsigned short* __restrict__ yv,
                          const int* __restrict__ t2r, const float* __restrict__ tkp,
                          float* __restrict__ outp) {
  int gid = blockIdx.x * 256 + threadIdx.x;
  int t = gid >> 8;
  int c4 = (gid & 255) << 2;
  int r0 = t2r[2 * t], r1 = t2r[2 * t + 1];
  float p0 = tkp[2 * t], p1 = tkp[2 * t + 1];
  ushort4v u0 = *(const ushort4v*)(yv + (size_t)r0 * DDIM + c4);
  ushort4v u1 = *(const ushort4v*)(yv + (size_t)r1 * DDIM + c4);
  float4 o;
  o.x = p0 * bf2f(u0.x) + p1 * bf2f(u1.x);
  o.y = p0 * bf2f(u0.y) + p1 * bf2f(u1.y);
  o.z = p0 * bf2f(u0.z) + p1 * bf2f(u1.z);
  o.w = p0 * bf2f(u0.w) + p1 * bf2f(u1.w);
  *(float4*)(outp + (size_t)t * DDIM + c4) = o;
}

extern "C" void kernel_launch(void* const* d_in, const int* in_sizes, int n_in,
                              void* d_out, int out_size, void* d_ws, size_t ws_size,
                              hipStream_t stream) {
  const float* x   = (const float*)d_in[0];
  const float* gw  = (const float*)d_in[1];
  const float* nwt = (const float*)d_in[2];
  const float* noi = (const float*)d_in[3];
  const float* w1  = (const float*)d_in[4];
  const float* b1  = (const float*)d_in[5];
  const float* w2  = (const float*)d_in[6];
  const float* b2  = (const float*)d_in[7];
  const float* wp  = (const float*)d_in[8];
  const float* bp  = (const float*)d_in[9];
  float* outp = (float*)d_out;
  char* ws = (char*)d_ws;

  constexpr size_t SZ_W = (size_t)EEXP * DDIM * HDIM * 2;
  constexpr size_t OFF_XB  = 0;
  constexpr size_t OFF_W1S = OFF_XB + (size_t)T_TOK * DDIM * 2;
  constexpr size_t OFF_W2S = OFF_W1S + SZ_W;
  constexpr size_t OFF_WPS = OFF_W2S + SZ_W;
  constexpr size_t OFF_H   = OFF_WPS + SZ_W;
  constexpr size_t OFF_Y   = OFF_H + (size_t)RMAX * HDIM * 2;
  constexpr size_t OFF_RT  = OFF_Y + (size_t)RMAX * DDIM * 2;
  constexpr size_t OFF_TKI = OFF_RT + (size_t)RMAX * 4;
  constexpr size_t OFF_TKP = OFF_TKI + (size_t)T_TOK * 2 * 4;
  constexpr size_t OFF_T2R = OFF_TKP + (size_t)T_TOK * 2 * 4;
  constexpr size_t OFF_CNT = OFF_T2R + (size_t)T_TOK * 2 * 4;
  constexpr size_t OFF_BAS = OFF_CNT + 256;
  constexpr size_t OFF_CUR = OFF_BAS + 256;
  // total ~407 MB

  unsigned short* xb  = (unsigned short*)(ws + OFF_XB);
  unsigned short* w1s = (unsigned short*)(ws + OFF_W1S);
  unsigned short* w2s = (unsigned short*)(ws + OFF_W2S);
  unsigned short* wps = (unsigned short*)(ws + OFF_WPS);
  unsigned short* h   = (unsigned short*)(ws + OFF_H);
  unsigned short* y   = (unsigned short*)(ws + OFF_Y);
  int*   rowtok = (int*)(ws + OFF_RT);
  int*   tki    = (int*)(ws + OFF_TKI);
  float* tkp    = (float*)(ws + OFF_TKP);
  int*   t2r    = (int*)(ws + OFF_T2R);
  int*   counts = (int*)(ws + OFF_CNT);
  int*   basep  = (int*)(ws + OFF_BAS);
  int*   cursor = (int*)(ws + OFF_CUR);

  dim3 blk(256);
  k_init<<<dim3((RMAX + 255) / 256), blk, 0, stream>>>(rowtok, counts, cursor);
  k_gate<<<dim3(T_TOK / 4), blk, 0, stream>>>(x, gw, nwt, noi, tki, tkp, counts, xb);
  k_convert_w<<<dim3(HDIM / 128, DDIM / 32, EEXP), blk, 0, stream>>>(w1, w1s, HDIM, DDIM);
  k_convert_w<<<dim3(HDIM / 128, DDIM / 32, EEXP), blk, 0, stream>>>(w2, w2s, HDIM, DDIM);
  k_convert_w<<<dim3(DDIM / 128, HDIM / 32, EEXP), blk, 0, stream>>>(wp, wps, DDIM, HDIM);
  k_prefix<<<dim3(1), dim3(64), 0, stream>>>(counts, basep);
  k_scatter<<<dim3(T_TOK / 256), blk, 0, stream>>>(tki, basep, cursor, rowtok, t2r);
  k_gemm1<<<dim3(HDIM / 128, EEXP * 64), dim3(512), 0, stream>>>(xb, w1s, w2s, b1, b2, counts, basep, rowtok, h);
  k_gemm2<<<dim3(DDIM / 256, EEXP * 64), dim3(512), 0, stream>>>(h, wps, bp, counts, basep, y);
  k_combine<<<dim3(T_TOK), blk, 0, stream>>>(y, t2r, tkp, outp);
  (void)in_sizes; (void)n_in; (void)out_size; (void)ws_size;
}

// Round 7
// 1028.864 us; speedup vs baseline: 1.0670x; 1.0115x over previous
//
#include <hip/hip_runtime.h>

// MoE: B=4,S=2048,D=1024,E=8,H=4096,K=2.  T = B*S = 8192 tokens.
// R7: R6 4-slot BK=32 pipeline with CONFLICT-FREE swizzle:
//   byte(r,kc) = (r*64) ^ (kc*16) ^ (((r>>1)&7)<<4)   (bijective, 2-way-free)
// applied to weight tiles (pre-swizzled), A-staging source (inverse map) and
// all ds_read offsets. Converts fused into one kernel.
// ws usage ~407 MB.

#define T_TOK 8192
#define DDIM 1024
#define EEXP 8
#define HDIM 4096
#define RMAX 18432   // T*K + E*256 padding

typedef short short8 __attribute__((ext_vector_type(8)));
typedef float f32x4 __attribute__((ext_vector_type(4)));
typedef unsigned short ushort4v __attribute__((ext_vector_type(4)));
typedef unsigned int u32;

__device__ __forceinline__ unsigned short f2bf(float f) {
  unsigned u = __builtin_bit_cast(unsigned, f);
  return (unsigned short)((u + 0x7FFFu + ((u >> 16) & 1u)) >> 16);
}
__device__ __forceinline__ float bf2f(unsigned short b) {
  unsigned u = ((unsigned)b) << 16;
  return __builtin_bit_cast(float, u);
}
__device__ __forceinline__ void gl_lds16(const void* g, void* l) {
  __builtin_amdgcn_global_load_lds((const u32 __attribute__((address_space(1)))*)g,
                                   (u32 __attribute__((address_space(3)))*)l, 16, 0, 0);
}
#define BAR() asm volatile("s_barrier" ::: "memory")
__device__ __forceinline__ void vwait_c(int n) {
  if (n == 8) asm volatile("s_waitcnt vmcnt(8)" ::: "memory");
  else if (n == 4) asm volatile("s_waitcnt vmcnt(4)" ::: "memory");
  else if (n == 0) asm volatile("s_waitcnt vmcnt(0)" ::: "memory");
}
#define MFMA_BF16 __builtin_amdgcn_mfma_f32_16x16x32_bf16

// in-tile swizzle for 64B rows (32 k-elems bf16), 16B chunks:
__device__ __forceinline__ int swz(int r, int kc16) {  // kc16 = kc*16
  return (r * 64) ^ kc16 ^ (((r >> 1) & 7) << 4);
}

// ---- weights: f32 [E][K][N] -> bf16 swizzled 8KB tiles, all 3 fused --------
// Tile = 128 n x 32 k; byte (n*64)^(kc*16)^(((n>>1)&7)<<4) holds B^T[n][kc*8..+7].
__global__ void k_convert_all(const float* __restrict__ w1, const float* __restrict__ w2,
                              const float* __restrict__ wp,
                              unsigned short* __restrict__ w1s, unsigned short* __restrict__ w2s,
                              unsigned short* __restrict__ wps) {
  __shared__ float lbuf[32][130];
  int bid = blockIdx.x;                 // 0..24575
  int seg = bid >> 13;                  // 0,1,2
  int t = bid & 8191;
  const float* src; unsigned short* dst; int N, K, ct, kt, e;
  e = t >> 10;
  if (seg < 2) {
    src = (seg == 0) ? w1 : w2; dst = (seg == 0) ? w1s : w2s;
    N = HDIM; K = DDIM; ct = (t >> 5) & 31; kt = t & 31;
  } else {
    src = wp; dst = wps;
    N = DDIM; K = HDIM; ct = (t >> 7) & 7; kt = t & 127;
  }
  int tid = threadIdx.x;
  const float* s = src + (size_t)e * K * N + (size_t)(kt * 32) * N + ct * 128;
#pragma unroll
  for (int q = 0; q < 4; q++) {
    int idx = q * 256 + tid;
    int row = idx >> 5, c4 = (idx & 31) * 4;
    float4 v = *(const float4*)(s + (size_t)row * N + c4);
    lbuf[row][c4 + 0] = v.x; lbuf[row][c4 + 1] = v.y;
    lbuf[row][c4 + 2] = v.z; lbuf[row][c4 + 3] = v.w;
  }
  __syncthreads();
  char* dt = (char*)dst + ((size_t)(e * (N / 128) + ct) * (K / 32) + kt) * 8192;
#pragma unroll
  for (int q = 0; q < 2; q++) {
    int idx = q * 256 + tid;
    int n = idx >> 2, kc = idx & 3;
    short8 o;
#pragma unroll
    for (int j = 0; j < 8; j++) o[j] = (short)f2bf(lbuf[kc * 8 + j][n]);
    *(short8*)(dt + swz(n, kc * 16)) = o;
  }
}

// ---- init ------------------------------------------------------------------
__global__ void k_init(int* __restrict__ rowtok, int* __restrict__ counts, int* __restrict__ cursor) {
  int i = blockIdx.x * 256 + threadIdx.x;
  if (i < RMAX) rowtok[i] = 0;
  if (i < EEXP) { counts[i] = 0; cursor[i] = 0; }
}

// ---- gating (+ fused x->bf16) ----------------------------------------------
__launch_bounds__(256)
__global__ void k_gate(const float* __restrict__ x, const float* __restrict__ gw,
                       const float* __restrict__ nwt, const float* __restrict__ noi,
                       int* __restrict__ tki, float* __restrict__ tkp,
                       int* __restrict__ counts, unsigned short* __restrict__ xb) {
  __shared__ float gwT[8][1024];
  int tid = threadIdx.x;
#pragma unroll
  for (int q = 0; q < 32; q++) {
    int flat = q * 256 + tid;
    gwT[flat & 7][flat >> 3] = gw[flat];
  }
  __syncthreads();
  int wave = tid >> 6, l = tid & 63;
  int t = blockIdx.x * 4 + wave;
  float acc[8] = {0.f, 0.f, 0.f, 0.f, 0.f, 0.f, 0.f, 0.f};
  const float4* xr = (const float4*)(x + (size_t)t * DDIM);
#pragma unroll
  for (int i = 0; i < 4; i++) {
    float4 xv = xr[l + i * 64];
    int d0 = (l + i * 64) * 4;
    ushort4v o;
    o.x = f2bf(xv.x); o.y = f2bf(xv.y); o.z = f2bf(xv.z); o.w = f2bf(xv.w);
    *(ushort4v*)(xb + (size_t)t * DDIM + d0) = o;
#pragma unroll
    for (int e = 0; e < 8; e++) {
      float4 gv = *(const float4*)&gwT[e][d0];
      acc[e] += xv.x * gv.x + xv.y * gv.y + xv.z * gv.z + xv.w * gv.w;
    }
  }
#pragma unroll
  for (int s = 1; s < 64; s <<= 1) {
#pragma unroll
    for (int e = 0; e < 8; e++) acc[e] += __shfl_xor(acc[e], s, 64);
  }
  if (l == 0) {
    float nl[8];
#pragma unroll
    for (int e = 0; e < 8; e++) nl[e] = acc[e] + noi[t * 8 + e] * nwt[e];
    int i0 = 0; float v0 = nl[0];
#pragma unroll
    for (int e = 1; e < 8; e++) if (nl[e] > v0) { v0 = nl[e]; i0 = e; }
    int i1 = -1; float v1 = -3.4e38f;
#pragma unroll
    for (int e = 0; e < 8; e++) if (e != i0 && nl[e] > v1) { v1 = nl[e]; i1 = e; }
    float ex = __expf(v1 - v0);
    float p0 = 1.f / (1.f + ex);
    float p1 = ex * p0;
    tki[2 * t] = i0; tki[2 * t + 1] = i1;
    tkp[2 * t] = p0; tkp[2 * t + 1] = p1;
    atomicAdd(&counts[i0], 1);
    atomicAdd(&counts[i1], 1);
  }
}

// ---- prefix (pad to 256-row tiles) -----------------------------------------
__global__ void k_prefix(const int* __restrict__ counts, int* __restrict__ basep) {
  if (threadIdx.x == 0) {
    int b = 0;
    for (int e = 0; e < EEXP; e++) { basep[e] = b; b += (counts[e] + 255) & ~255; }
  }
}

// ---- scatter ---------------------------------------------------------------
__global__ void k_scatter(const int* __restrict__ tki, const int* __restrict__ basep,
                          int* __restrict__ cursor, int* __restrict__ rowtok,
                          int* __restrict__ t2r) {
  int t = blockIdx.x * 256 + threadIdx.x;
  if (t >= T_TOK) return;
#pragma unroll
  for (int k = 0; k < 2; k++) {
    int e = tki[2 * t + k];
    int pos = atomicAdd(&cursor[e], 1);
    int row = basep[e] + pos;
    rowtok[row] = t;
    t2r[2 * t + k] = row;
  }
}

// staging inverse map: dest chunk c -> (row r, k-chunk kc)
#define INV_MAP(c, r, kc) { int _h = (c) >> 3;                                   \
    r = 2 * _h + ((((c) >> 2) ^ (_h >> 2)) & 1);                                 \
    kc = ((c) & 3) ^ (_h & 3); }

// ---- GEMM1: BM=256, dual-B 128 cols each, BK=32, 4 slots, 3-deep -----------
__launch_bounds__(512, 2)
__global__ void k_gemm1(const unsigned short* __restrict__ xb,
                        const unsigned short* __restrict__ w1s, const unsigned short* __restrict__ w2s,
                        const float* __restrict__ b1g, const float* __restrict__ b2g,
                        const int* __restrict__ counts, const int* __restrict__ basep,
                        const int* __restrict__ rowtok,
                        unsigned short* __restrict__ hout) {
  int e = blockIdx.y >> 6;
  int rt = blockIdx.y & 63;
  int cnt = counts[e];
  if (rt >= ((cnt + 255) >> 8)) return;
  int ct = blockIdx.x;              // 0..31 over H
  int row0 = basep[e] + rt * 256;
  int col0 = ct * 128;

  __shared__ char smem[131072];     // A 4x16KB @0 | B1 4x8KB @65536 | B2 4x8KB @98304
  __shared__ int s_tok[256];
  __shared__ float s_b1[128], s_b2[128];

  int tid = threadIdx.x;
  if (tid < 256) s_tok[tid] = rowtok[row0 + tid];
  if (tid < 128) {
    s_b1[tid] = b1g[e * HDIM + col0 + tid];
    s_b2[tid] = b2g[e * HDIM + col0 + tid];
  }
  __syncthreads();

  int wave = tid >> 6, l = tid & 63;
  int wm = wave >> 2, wn = wave & 3;          // 2M x 4N
  int g = l >> 4, ln = l & 15;

  // A staging: 2 chunks/thread, dest linear, source via inverse swizzle map
  int c0 = tid, c1 = 512 + tid;
  int r0, kc0, r1, kc1;
  INV_MAP(c0, r0, kc0) INV_MAP(c1, r1, kc1)
  size_t a_src0 = (size_t)s_tok[r0] * 2048 + (size_t)(kc0 * 16);
  size_t a_src1 = (size_t)s_tok[r1] * 2048 + (size_t)(kc1 * 16);
  int a_dst0 = c0 * 16, a_dst1 = c1 * 16;

  int a_rd[8];
#pragma unroll
  for (int m = 0; m < 8; m++) {
    int r = wm * 128 + m * 16 + ln;
    a_rd[m] = swz(r, g * 16);
  }
  int b_rd[2];
#pragma unroll
  for (int n = 0; n < 2; n++) {
    int r = wn * 32 + n * 16 + ln;
    b_rd[n] = swz(r, g * 16);
  }

  f32x4 zero = {0.f, 0.f, 0.f, 0.f};
  f32x4 acc_a[8][2], acc_b[8][2];
#pragma unroll
  for (int m = 0; m < 8; m++)
#pragma unroll
    for (int n = 0; n < 2; n++) { acc_a[m][n] = zero; acc_b[m][n] = zero; }

  const char* xbb = (const char*)xb;
  const char* w1t = (const char*)w1s + (size_t)(e * 32 + ct) * 32 * 8192;
  const char* w2t = (const char*)w2s + (size_t)(e * 32 + ct) * 32 * 8192;

#define G1_PRE(s) { int nb = (s) & 3;                                            \
    gl_lds16(xbb + a_src0 + (size_t)(s) * 64, smem + nb * 16384 + a_dst0);       \
    gl_lds16(xbb + a_src1 + (size_t)(s) * 64, smem + nb * 16384 + a_dst1);       \
    gl_lds16(w1t + (size_t)(s) * 8192 + tid * 16, smem + 65536 + nb * 8192 + tid * 16); \
    gl_lds16(w2t + (size_t)(s) * 8192 + tid * 16, smem + 98304 + nb * 8192 + tid * 16); }

  G1_PRE(0) G1_PRE(1) G1_PRE(2)
  vwait_c(8); BAR();

#define G1_SLOT(s, ISSUE, VMN) {                                                 \
    int bs = (s) & 3;                                                            \
    char* Ab = smem + bs * 16384;                                                \
    char* B1b = smem + 65536 + bs * 8192;                                        \
    char* B2b = smem + 98304 + bs * 8192;                                        \
    short8 af[4], b1f[2], b2f[2];                                                \
    _Pragma("unroll") for (int m = 0; m < 4; m++) af[m] = *(const short8*)(Ab + a_rd[m]); \
    b1f[0] = *(const short8*)(B1b + b_rd[0]); b1f[1] = *(const short8*)(B1b + b_rd[1]); \
    b2f[0] = *(const short8*)(B2b + b_rd[0]); b2f[1] = *(const short8*)(B2b + b_rd[1]); \
    if (ISSUE) { int ns = (s) + 3, nb = ns & 3;                                  \
      gl_lds16(xbb + a_src0 + (size_t)ns * 64, smem + nb * 16384 + a_dst0);      \
      gl_lds16(xbb + a_src1 + (size_t)ns * 64, smem + nb * 16384 + a_dst1); }    \
    BAR();                                                                       \
    __builtin_amdgcn_s_setprio(1);                                               \
    _Pragma("unroll") for (int m = 0; m < 4; m++) {                              \
      acc_a[m][0] = MFMA_BF16(af[m], b1f[0], acc_a[m][0], 0, 0, 0);              \
      acc_a[m][1] = MFMA_BF16(af[m], b1f[1], acc_a[m][1], 0, 0, 0);              \
      acc_b[m][0] = MFMA_BF16(af[m], b2f[0], acc_b[m][0], 0, 0, 0);              \
      acc_b[m][1] = MFMA_BF16(af[m], b2f[1], acc_b[m][1], 0, 0, 0); }            \
    __builtin_amdgcn_s_setprio(0);                                               \
    BAR();                                                                       \
    _Pragma("unroll") for (int m = 0; m < 4; m++) af[m] = *(const short8*)(Ab + a_rd[4 + m]); \
    if (ISSUE) { int ns = (s) + 3, nb = ns & 3;                                  \
      gl_lds16(w1t + (size_t)ns * 8192 + tid * 16, smem + 65536 + nb * 8192 + tid * 16); \
      gl_lds16(w2t + (size_t)ns * 8192 + tid * 16, smem + 98304 + nb * 8192 + tid * 16); } \
    BAR();                                                                       \
    __builtin_amdgcn_s_setprio(1);                                               \
    _Pragma("unroll") for (int m = 0; m < 4; m++) {                              \
      acc_a[4 + m][0] = MFMA_BF16(af[m], b1f[0], acc_a[4 + m][0], 0, 0, 0);      \
      acc_a[4 + m][1] = MFMA_BF16(af[m], b1f[1], acc_a[4 + m][1], 0, 0, 0);      \
      acc_b[4 + m][0] = MFMA_BF16(af[m], b2f[0], acc_b[4 + m][0], 0, 0, 0);      \
      acc_b[4 + m][1] = MFMA_BF16(af[m], b2f[1], acc_b[4 + m][1], 0, 0, 0); }    \
    __builtin_amdgcn_s_setprio(0);                                               \
    vwait_c(VMN); BAR(); }

  for (int s = 0; s < 29; ++s) { G1_SLOT(s, 1, 8) }
  G1_SLOT(29, 0, 4)
  G1_SLOT(30, 0, 0)
  G1_SLOT(31, 0, -1)

  __syncthreads();
  // epilogue: SwiGLU -> bf16 tile (256x128) in LDS, coalesced stores
  unsigned short* ht = (unsigned short*)smem;
#pragma unroll
  for (int m = 0; m < 8; m++)
#pragma unroll
    for (int n = 0; n < 2; n++)
#pragma unroll
      for (int r = 0; r < 4; r++) {
        int row = wm * 128 + m * 16 + g * 4 + r;
        int col = wn * 32 + n * 16 + ln;
        float a = acc_a[m][n][r] + s_b1[col];
        float b = acc_b[m][n][r] + s_b2[col];
        float hv = a * (b / (1.f + __expf(-b)));
        ht[row * 128 + col] = f2bf(hv);
      }
  __syncthreads();
#pragma unroll
  for (int q = 0; q < 8; q++) {
    int idx = q * 512 + tid;          // 4096 chunks; 16 per 256B row
    int row = idx >> 4, cc = (idx & 15) * 8;
    short8 v = *(const short8*)(smem + idx * 16);
    *(short8*)(hout + (size_t)(row0 + row) * HDIM + col0 + cc) = v;
  }
}

// ---- GEMM2: BM=256, BN=256, BK=32, 4 slots, 3-deep pipeline ----------------
__launch_bounds__(512, 2)
__global__ void k_gemm2(const unsigned short* __restrict__ hin,
                        const unsigned short* __restrict__ wps, const float* __restrict__ bpg,
                        const int* __restrict__ counts, const int* __restrict__ basep,
                        unsigned short* __restrict__ yout) {
  int e = blockIdx.y >> 6;
  int rt = blockIdx.y & 63;
  int cnt = counts[e];
  if (rt >= ((cnt + 255) >> 8)) return;
  int ct = blockIdx.x;              // 0..3 over D (256 cols)
  int row0 = basep[e] + rt * 256;
  int col0 = ct * 256;

  __shared__ char smem[131072];     // A 4x16KB @0 | B 4x16KB @65536
  __shared__ float s_bp[256];
  int tid = threadIdx.x;
  if (tid < 256) s_bp[tid] = bpg[e * DDIM + col0 + tid];
  __syncthreads();

  int wave = tid >> 6, l = tid & 63;
  int wm = wave >> 2, wn = wave & 3;          // 2M x 4N -> per wave 128x64
  int g = l >> 4, ln = l & 15;

  int c0 = tid, c1 = 512 + tid;
  int r0, kc0, r1, kc1;
  INV_MAP(c0, r0, kc0) INV_MAP(c1, r1, kc1)
  size_t a_src0 = (size_t)(row0 + r0) * 8192 + (size_t)(kc0 * 16);
  size_t a_src1 = (size_t)(row0 + r1) * 8192 + (size_t)(kc1 * 16);
  int a_dst0 = c0 * 16, a_dst1 = c1 * 16;
  // B staging: sub-tile 0 via c0-chunk, sub-tile 1 via c1-chunk (both linear)
  const char* b_src0 = (const char*)wps + (size_t)(e * 8 + ct * 2 + 0) * 128 * 8192 + (size_t)tid * 16;
  const char* b_src1 = (const char*)wps + (size_t)(e * 8 + ct * 2 + 1) * 128 * 8192 + (size_t)tid * 16;

  int a_rd[8];
#pragma unroll
  for (int m = 0; m < 8; m++) {
    int r = wm * 128 + m * 16 + ln;
    a_rd[m] = swz(r, g * 16);
  }
  int b_rd[4];
#pragma unroll
  for (int n = 0; n < 4; n++) {
    int ncol = wn * 64 + n * 16 + ln;
    int sub = ncol >> 7, r = ncol & 127;
    b_rd[n] = sub * 8192 + swz(r, g * 16);
  }

  f32x4 zero = {0.f, 0.f, 0.f, 0.f};
  f32x4 acc[8][4];
#pragma unroll
  for (int m = 0; m < 8; m++)
#pragma unroll
    for (int n = 0; n < 4; n++) acc[m][n] = zero;

  const char* hb = (const char*)hin;

#define G2_PRE(s) { int nb = (s) & 3;                                            \
    gl_lds16(hb + a_src0 + (size_t)(s) * 64, smem + nb * 16384 + a_dst0);        \
    gl_lds16(hb + a_src1 + (size_t)(s) * 64, smem + nb * 16384 + a_dst1);        \
    gl_lds16(b_src0 + (size_t)(s) * 8192, smem + 65536 + nb * 16384 + tid * 16); \
    gl_lds16(b_src1 + (size_t)(s) * 8192, smem + 65536 + nb * 16384 + 8192 + tid * 16); }

  G2_PRE(0) G2_PRE(1) G2_PRE(2)
  vwait_c(8); BAR();

#define G2_SLOT(s, ISSUE, VMN) {                                                 \
    int bs = (s) & 3;                                                            \
    char* Ab = smem + bs * 16384;                                                \
    char* Bb = smem + 65536 + bs * 16384;                                        \
    short8 af[4], bf[4];                                                         \
    _Pragma("unroll") for (int m = 0; m < 4; m++) af[m] = *(const short8*)(Ab + a_rd[m]); \
    _Pragma("unroll") for (int n = 0; n < 4; n++) bf[n] = *(const short8*)(Bb + b_rd[n]); \
    if (ISSUE) { int ns = (s) + 3, nb = ns & 3;                                  \
      gl_lds16(hb + a_src0 + (size_t)ns * 64, smem + nb * 16384 + a_dst0);       \
      gl_lds16(hb + a_src1 + (size_t)ns * 64, smem + nb * 16384 + a_dst1); }     \
    BAR();                                                                       \
    __builtin_amdgcn_s_setprio(1);                                               \
    _Pragma("unroll") for (int m = 0; m < 4; m++)                                \
      _Pragma("unroll") for (int n = 0; n < 4; n++)                              \
        acc[m][n] = MFMA_BF16(af[m], bf[n], acc[m][n], 0, 0, 0);                 \
    __builtin_amdgcn_s_setprio(0);                                               \
    BAR();                                                                       \
    _Pragma("unroll") for (int m = 0; m < 4; m++) af[m] = *(const short8*)(Ab + a_rd[4 + m]); \
    if (ISSUE) { int ns = (s) + 3, nb = ns & 3;                                  \
      gl_lds16(b_src0 + (size_t)ns * 8192, smem + 65536 + nb * 16384 + tid * 16);\
      gl_lds16(b_src1 + (size_t)ns * 8192, smem + 65536 + nb * 16384 + 8192 + tid * 16); }\
    BAR();                                                                       \
    __builtin_amdgcn_s_setprio(1);                                               \
    _Pragma("unroll") for (int m = 0; m < 4; m++)                                \
      _Pragma("unroll") for (int n = 0; n < 4; n++)                              \
        acc[4 + m][n] = MFMA_BF16(af[m], bf[n], acc[4 + m][n], 0, 0, 0);         \
    __builtin_amdgcn_s_setprio(0);                                               \
    vwait_c(VMN); BAR(); }

  for (int s = 0; s < 125; ++s) { G2_SLOT(s, 1, 8) }
  G2_SLOT(125, 0, 4)
  G2_SLOT(126, 0, 0)
  G2_SLOT(127, 0, -1)

  __syncthreads();
  // epilogue: 256x256 bf16 tile in LDS, coalesced stores
  unsigned short* ht = (unsigned short*)smem;
#pragma unroll
  for (int m = 0; m < 8; m++)
#pragma unroll
    for (int n = 0; n < 4; n++)
#pragma unroll
      for (int r = 0; r < 4; r++) {
        int row = wm * 128 + m * 16 + g * 4 + r;
        int col = wn * 64 + n * 16 + ln;
        ht[row * 256 + col] = f2bf(acc[m][n][r] + s_bp[col]);
      }
  __syncthreads();
#pragma unroll
  for (int q = 0; q < 16; q++) {
    int idx = q * 512 + tid;          // 8192 chunks; 32 per 512B row
    int row = idx >> 5, cc = (idx & 31) * 8;
    short8 v = *(const short8*)(smem + idx * 16);
    *(short8*)(yout + (size_t)(row0 + row) * DDIM + col0 + cc) = v;
  }
}

// ---- combine ---------------------------------------------------------------
__global__ void k_combine(const unsigned short* __restrict__ yv,
                          const int* __restrict__ t2r, const float* __restrict__ tkp,
                          float* __restrict__ outp) {
  int gid = blockIdx.x * 256 + threadIdx.x;
  int t = gid >> 8;
  int c4 = (gid & 255) << 2;
  int r0 = t2r[2 * t], r1 = t2r[2 * t + 1];
  float p0 = tkp[2 * t], p1 = tkp[2 * t + 1];
  ushort4v u0 = *(const ushort4v*)(yv + (size_t)r0 * DDIM + c4);
  ushort4v u1 = *(const ushort4v*)(yv + (size_t)r1 * DDIM + c4);
  float4 o;
  o.x = p0 * bf2f(u0.x) + p1 * bf2f(u1.x);
  o.y = p0 * bf2f(u0.y) + p1 * bf2f(u1.y);
  o.z = p0 * bf2f(u0.z) + p1 * bf2f(u1.z);
  o.w = p0 * bf2f(u0.w) + p1 * bf2f(u1.w);
  *(float4*)(outp + (size_t)t * DDIM + c4) = o;
}

extern "C" void kernel_launch(void* const* d_in, const int* in_sizes, int n_in,
                              void* d_out, int out_size, void* d_ws, size_t ws_size,
                              hipStream_t stream) {
  const float* x   = (const float*)d_in[0];
  const float* gw  = (const float*)d_in[1];
  const float* nwt = (const float*)d_in[2];
  const float* noi = (const float*)d_in[3];
  const float* w1  = (const float*)d_in[4];
  const float* b1  = (const float*)d_in[5];
  const float* w2  = (const float*)d_in[6];
  const float* b2  = (const float*)d_in[7];
  const float* wp  = (const float*)d_in[8];
  const float* bp  = (const float*)d_in[9];
  float* outp = (float*)d_out;
  char* ws = (char*)d_ws;

  constexpr size_t SZ_W = (size_t)EEXP * DDIM * HDIM * 2;
  constexpr size_t OFF_XB  = 0;
  constexpr size_t OFF_W1S = OFF_XB + (size_t)T_TOK * DDIM * 2;
  constexpr size_t OFF_W2S = OFF_W1S + SZ_W;
  constexpr size_t OFF_WPS = OFF_W2S + SZ_W;
  constexpr size_t OFF_H   = OFF_WPS + SZ_W;
  constexpr size_t OFF_Y   = OFF_H + (size_t)RMAX * HDIM * 2;
  constexpr size_t OFF_RT  = OFF_Y + (size_t)RMAX * DDIM * 2;
  constexpr size_t OFF_TKI = OFF_RT + (size_t)RMAX * 4;
  constexpr size_t OFF_TKP = OFF_TKI + (size_t)T_TOK * 2 * 4;
  constexpr size_t OFF_T2R = OFF_TKP + (size_t)T_TOK * 2 * 4;
  constexpr size_t OFF_CNT = OFF_T2R + (size_t)T_TOK * 2 * 4;
  constexpr size_t OFF_BAS = OFF_CNT + 256;
  constexpr size_t OFF_CUR = OFF_BAS + 256;
  // total ~407 MB

  unsigned short* xb  = (unsigned short*)(ws + OFF_XB);
  unsigned short* w1s = (unsigned short*)(ws + OFF_W1S);
  unsigned short* w2s = (unsigned short*)(ws + OFF_W2S);
  unsigned short* wps = (unsigned short*)(ws + OFF_WPS);
  unsigned short* h   = (unsigned short*)(ws + OFF_H);
  unsigned short* y   = (unsigned short*)(ws + OFF_Y);
  int*   rowtok = (int*)(ws + OFF_RT);
  int*   tki    = (int*)(ws + OFF_TKI);
  float* tkp    = (float*)(ws + OFF_TKP);
  int*   t2r    = (int*)(ws + OFF_T2R);
  int*   counts = (int*)(ws + OFF_CNT);
  int*   basep  = (int*)(ws + OFF_BAS);
  int*   cursor = (int*)(ws + OFF_CUR);

  dim3 blk(256);
  k_init<<<dim3((RMAX + 255) / 256), blk, 0, stream>>>(rowtok, counts, cursor);
  k_gate<<<dim3(T_TOK / 4), blk, 0, stream>>>(x, gw, nwt, noi, tki, tkp, counts, xb);
  k_convert_all<<<dim3(24576), blk, 0, stream>>>(w1, w2, wp, w1s, w2s, wps);
  k_prefix<<<dim3(1), dim3(64), 0, stream>>>(counts, basep);
  k_scatter<<<dim3(T_TOK / 256), blk, 0, stream>>>(tki, basep, cursor, rowtok, t2r);
  k_gemm1<<<dim3(HDIM / 128, EEXP * 64), dim3(512), 0, stream>>>(xb, w1s, w2s, b1, b2, counts, basep, rowtok, h);
  k_gemm2<<<dim3(DDIM / 256, EEXP * 64), dim3(512), 0, stream>>>(h, wps, bp, counts, basep, y);
  k_combine<<<dim3(T_TOK), blk, 0, stream>>>(y, t2r, tkp, outp);
  (void)in_sizes; (void)n_in; (void)out_size; (void)ws_size;
}